// Round 2
// baseline (2459.272 us; speedup 1.0000x reference)
//
#include <hip/hip_runtime.h>

#define HH 192
#define WW 192
#define PW 194
#define HWSZ (HH*WW)        // 36864
#define PHW (PW*PW)         // 37636
#define CHW (64*HWSZ)       // 2359296 per frame

typedef __attribute__((ext_vector_type(8))) short bf16x8;
typedef __attribute__((ext_vector_type(4))) short bf16x4;
typedef __attribute__((ext_vector_type(4))) float f32x4;
typedef __attribute__((ext_vector_type(4))) unsigned int u32x4;

typedef __attribute__((address_space(3))) void as3_void;
typedef __attribute__((address_space(1))) const void as1_cvoid;

__device__ __forceinline__ float bf2f(short h) {
    union { unsigned u; float f; } c; c.u = ((unsigned)(unsigned short)h) << 16; return c.f;
}
__device__ __forceinline__ short f2bf(float f) {
    union { float f; unsigned u; } c; c.f = f;
    unsigned u = c.u;
    return (short)((u + 0x7FFFu + ((u >> 16) & 1u)) >> 16);
}

// ---------------------------------------------------------------------------
// Stage a 3x98-cell x 64-channel bf16 tile into LDS via global_load_lds(16B).
// LDS layout is linear in chunk index q (byte q*16); the XOR slot-swizzle is
// applied on the SOURCE address (m173 pattern): LDS slot s of cell (r,col)
// receives channel-sub s^(col&7). 2368 chunks (37,888 B), tail clamped.
// ---------------------------------------------------------------------------
__device__ __forceinline__ void stage98(short* lds, const short* src, int cs, int cb,
                                        int y, int x0, int wv, int l)
{
    const int d = l >> 3, s = l & 7;
#pragma unroll 1
    for (int g = wv; g < 37; g += 2) {
        int cell = g*8 + d;
        if (cell > 293) cell = 293;
        int r = (cell*669) >> 16;            // cell/98 for cell<294
        int col = cell - r*98;
        const short* gp = src + (size_t)((y + r)*PW + (x0 + col))*cs + cb + (s ^ (col & 7))*8;
        __builtin_amdgcn_global_load_lds((as1_cvoid*)gp, (as3_void*)(lds + g*512), 16, 0, 0);
    }
}

// ---------------------------------------------------------------------------
// Implicit-GEMM 3x3 SAME conv over padded-NHWC bf16 activations.
// BM=64*MTN couts, BN=96 pixels (half row), 2 waves. K staged in 64-cin blocks.
// wt layout: [9 taps][COUT][CIN] bf16 (cin contiguous).
// EPI: 0 = bias(+lrelu) -> bf16 store; 2 = gate1 (p1*sig -> f32 aux);
//      3 = gate2 (p2*sig + aux -> d_out NCHW f32 + fp_state padded bf16)
// ---------------------------------------------------------------------------
template<int CIN, int COUT, int MTN, int EPI>
__global__ __launch_bounds__(128, 2)
void convk(const short* __restrict__ in0, int cs0, int cb0,
           const short* __restrict__ in1, int cs1, int cb1,
           const short* __restrict__ wt, const float* __restrict__ bias,
           short* __restrict__ outb, int pado, int rowW, int cdst, int lrelu,
           const short* __restrict__ fus, int fcb,
           float* __restrict__ taux, float* __restrict__ dml,
           short* __restrict__ fpst)
{
    constexpr int KB = CIN / 64;
    __shared__ __align__(16) short lds[2368*8];   // 37,888 B
    const int tid = threadIdx.x;
    const int l  = tid & 63, wv = tid >> 6;
    const int lr = l & 15,  lg = l >> 4;
    int bx = blockIdx.x;
    const int nt = bx & 1; bx >>= 1;
    const int y  = bx % HH;
    const int mtg = bx / HH;
    const int x0 = nt * 96;

    f32x4 acc[MTN][4][3];
#pragma unroll
    for (int m = 0; m < MTN; ++m)
#pragma unroll
        for (int a = 0; a < 4; ++a)
#pragma unroll
            for (int b = 0; b < 3; ++b) acc[m][a][b] = f32x4{0.f,0.f,0.f,0.f};

#pragma unroll 1
    for (int kb = 0; kb < KB; ++kb) {
        const short* src = (kb == 0) ? in0 : in1;
        const int cs = (kb == 0) ? cs0 : cs1;
        const int cb = (kb == 0) ? cb0 : cb1;
        stage98(lds, src, cs, cb, y, x0, wv, l);
        __syncthreads();
#pragma unroll
        for (int mt = 0; mt < MTN; ++mt) {
#pragma unroll
            for (int dy = 0; dy < 3; ++dy) {
#pragma unroll
                for (int dx = 0; dx < 3; ++dx) {
                    const short* wtap = wt + ((size_t)(dy*3+dx)*COUT + (mtg*MTN+mt)*64 + lr)*CIN + kb*64 + lg*8;
#pragma unroll
                    for (int ks = 0; ks < 2; ++ks) {
                        bf16x8 a0 = *reinterpret_cast<const bf16x8*>(wtap + ks*32);
                        bf16x8 a1 = *reinterpret_cast<const bf16x8*>(wtap + 16*CIN + ks*32);
                        bf16x8 a2 = *reinterpret_cast<const bf16x8*>(wtap + 32*CIN + ks*32);
                        bf16x8 a3 = *reinterpret_cast<const bf16x8*>(wtap + 48*CIN + ks*32);
#pragma unroll
                        for (int nf = 0; nf < 3; ++nf) {
                            int colc = wv*48 + nf*16 + lr + dx;
                            int slot = (ks*4 + lg) ^ (colc & 7);
                            bf16x8 bv = *reinterpret_cast<const bf16x8*>(&lds[((dy*98 + colc)*8 + slot)*8]);
                            acc[mt][0][nf] = __builtin_amdgcn_mfma_f32_16x16x32_bf16(a0, bv, acc[mt][0][nf], 0,0,0);
                            acc[mt][1][nf] = __builtin_amdgcn_mfma_f32_16x16x32_bf16(a1, bv, acc[mt][1][nf], 0,0,0);
                            acc[mt][2][nf] = __builtin_amdgcn_mfma_f32_16x16x32_bf16(a2, bv, acc[mt][2][nf], 0,0,0);
                            acc[mt][3][nf] = __builtin_amdgcn_mfma_f32_16x16x32_bf16(a3, bv, acc[mt][3][nf], 0,0,0);
                        }
                    }
                }
            }
        }
        if (kb + 1 < KB) __syncthreads();
    }

    // ---- epilogue: D row = lg*4 + j (+mf*16+tile*64), col = lr ----
#pragma unroll
    for (int mt = 0; mt < MTN; ++mt)
#pragma unroll
    for (int mf = 0; mf < 4; ++mf) {
        const int coutb = (mtg*MTN+mt)*64 + mf*16 + lg*4;
        f32x4 bv = *reinterpret_cast<const f32x4*>(bias + coutb);
#pragma unroll
        for (int nf = 0; nf < 3; ++nf) {
            const int x = x0 + wv*48 + nf*16 + lr;
            f32x4 v = acc[mt][mf][nf];
            if constexpr (EPI == 0) {
                bf16x4 pk;
#pragma unroll
                for (int j = 0; j < 4; ++j) {
                    float t = v[j] + bv[j];
                    if (lrelu) t = (t >= 0.f) ? t : 0.1f*t;
                    pk[j] = f2bf(t);
                }
                *reinterpret_cast<bf16x4*>(outb + (size_t)((y+pado)*rowW + (x+pado))*cdst + coutb) = pk;
            } else if constexpr (EPI == 2) {
                bf16x4 pv = *reinterpret_cast<const bf16x4*>(fus + (size_t)((y+1)*PW + (x+1))*128 + fcb + coutb);
                f32x4 o;
#pragma unroll
                for (int j = 0; j < 4; ++j) {
                    float g = 1.f / (1.f + __expf(-(v[j] + bv[j])));
                    o[j] = bf2f(pv[j]) * g;
                }
                *reinterpret_cast<f32x4*>(taux + (size_t)(y*WW + x)*64 + coutb) = o;
            } else {  // EPI == 3
                bf16x4 pv = *reinterpret_cast<const bf16x4*>(fus + (size_t)((y+1)*PW + (x+1))*128 + fcb + coutb);
                f32x4 tv = *reinterpret_cast<const f32x4*>(taux + (size_t)(y*WW + x)*64 + coutb);
                bf16x4 pk;
#pragma unroll
                for (int j = 0; j < 4; ++j) {
                    float g = 1.f / (1.f + __expf(-(v[j] + bv[j])));
                    float r = bf2f(pv[j]) * g + tv[j];
                    dml[(size_t)(coutb + j)*HWSZ + y*WW + x] = r;
                    pk[j] = f2bf(r);
                }
                *reinterpret_cast<bf16x4*>(fpst + (size_t)((y+1)*PW + (x+1))*64 + coutb) = pk;
            }
        }
    }
}

// ---------------------------------------------------------------------------
// FUSED kc2-conv + kernel_conv. Cout tile mt of the 576-wide conv IS
// kernel_conv tap mt=(my,mx). Per mt: 216 MFMA produce kp[mt*64+c, pix];
// facc[c,pix] += (kp+bias) * fp_pad[y+my, x+mx, c]. kp never materialized.
// ---------------------------------------------------------------------------
__global__ __launch_bounds__(128, 2)
void kckconvk(const short* __restrict__ tin, const short* __restrict__ wt,
              const float* __restrict__ bias, const short* __restrict__ fp,
              short* __restrict__ outp)
{
    __shared__ __align__(16) short lds[2368*8];
    const int tid = threadIdx.x;
    const int l  = tid & 63, wv = tid >> 6;
    const int lr = l & 15,  lg = l >> 4;
    int bx = blockIdx.x;
    const int nt = bx & 1;
    const int y  = bx >> 1;
    const int x0 = nt * 96;

    stage98(lds, tin, 64, 0, y, x0, wv, l);

    f32x4 facc[4][3];
#pragma unroll
    for (int a = 0; a < 4; ++a)
#pragma unroll
        for (int b = 0; b < 3; ++b) facc[a][b] = f32x4{0.f,0.f,0.f,0.f};

    __syncthreads();

#pragma unroll 1
    for (int mt = 0; mt < 9; ++mt) {
        const int my = mt / 3, mx = mt - my*3;
        // fp loads for this tap — issue early, consumed after the MFMAs
        bf16x4 fpv[4][3];
#pragma unroll
        for (int mf = 0; mf < 4; ++mf)
#pragma unroll
            for (int nf = 0; nf < 3; ++nf)
                fpv[mf][nf] = *reinterpret_cast<const bf16x4*>(
                    fp + (size_t)((y+my)*PW + (x0 + wv*48 + nf*16 + lr + mx))*64 + mf*16 + lg*4);

        f32x4 acc[4][3];
#pragma unroll
        for (int a = 0; a < 4; ++a)
#pragma unroll
            for (int b = 0; b < 3; ++b) acc[a][b] = f32x4{0.f,0.f,0.f,0.f};

#pragma unroll
        for (int tp = 0; tp < 9; ++tp) {
            const int ty = tp / 3, tx = tp - ty*3;
            const short* wtap = wt + ((size_t)tp*576 + mt*64 + lr)*64 + lg*8;
#pragma unroll
            for (int ks = 0; ks < 2; ++ks) {
                bf16x8 a0 = *reinterpret_cast<const bf16x8*>(wtap + ks*32);
                bf16x8 a1 = *reinterpret_cast<const bf16x8*>(wtap + 16*64 + ks*32);
                bf16x8 a2 = *reinterpret_cast<const bf16x8*>(wtap + 32*64 + ks*32);
                bf16x8 a3 = *reinterpret_cast<const bf16x8*>(wtap + 48*64 + ks*32);
#pragma unroll
                for (int nf = 0; nf < 3; ++nf) {
                    int colc = wv*48 + nf*16 + lr + tx;
                    int slot = (ks*4 + lg) ^ (colc & 7);
                    bf16x8 bv = *reinterpret_cast<const bf16x8*>(&lds[((ty*98 + colc)*8 + slot)*8]);
                    acc[0][nf] = __builtin_amdgcn_mfma_f32_16x16x32_bf16(a0, bv, acc[0][nf], 0,0,0);
                    acc[1][nf] = __builtin_amdgcn_mfma_f32_16x16x32_bf16(a1, bv, acc[1][nf], 0,0,0);
                    acc[2][nf] = __builtin_amdgcn_mfma_f32_16x16x32_bf16(a2, bv, acc[2][nf], 0,0,0);
                    acc[3][nf] = __builtin_amdgcn_mfma_f32_16x16x32_bf16(a3, bv, acc[3][nf], 0,0,0);
                }
            }
        }
#pragma unroll
        for (int mf = 0; mf < 4; ++mf) {
            f32x4 bv = *reinterpret_cast<const f32x4*>(bias + mt*64 + mf*16 + lg*4);
#pragma unroll
            for (int nf = 0; nf < 3; ++nf)
#pragma unroll
                for (int j = 0; j < 4; ++j)
                    facc[mf][nf][j] += (acc[mf][nf][j] + bv[j]) * bf2f(fpv[mf][nf][j]);
        }
    }

    // ---- store fpmid (padded NHWC bf16, interior) ----
#pragma unroll
    for (int mf = 0; mf < 4; ++mf)
#pragma unroll
        for (int nf = 0; nf < 3; ++nf) {
            const int x = x0 + wv*48 + nf*16 + lr;
            bf16x4 pk;
#pragma unroll
            for (int j = 0; j < 4; ++j) pk[j] = f2bf(facc[mf][nf][j]);
            *reinterpret_cast<bf16x4*>(outp + (size_t)((y+1)*PW + (x+1))*64 + mf*16 + lg*4) = pk;
        }
}

// ---------------------------------------------------------------------------
// NCHW f32 frame -> padded NHWC bf16 (interior only; border pre-zeroed)
// ---------------------------------------------------------------------------
__global__ __launch_bounds__(64)
void tonhwck(const float* __restrict__ src, short* __restrict__ dst)
{
    int b = blockIdx.x;
    int y = b / 3, x = (b - y*3)*64 + threadIdx.x;
    unsigned pk[32];
#pragma unroll
    for (int c = 0; c < 64; ++c) {
        unsigned h = (unsigned)(unsigned short)f2bf(src[(size_t)c*HWSZ + y*WW + x]);
        if (c & 1) pk[c>>1] |= h << 16; else pk[c>>1] = h;
    }
    u32x4* d = reinterpret_cast<u32x4*>(dst + (size_t)((y+1)*PW + (x+1))*64);
#pragma unroll
    for (int q = 0; q < 8; ++q) d[q] = u32x4{pk[4*q], pk[4*q+1], pk[4*q+2], pk[4*q+3]};
}

// ---------------------------------------------------------------------------
// weight [COUT][CIN][3][3] f32 -> [9][COUT][CIN] bf16
// ---------------------------------------------------------------------------
__global__ void wtxk(const float* __restrict__ src, short* __restrict__ dst,
                     int cout_n, int cin_n)
{
    int i = blockIdx.x*256 + threadIdx.x;
    if (i >= cout_n*cin_n) return;
    int co = i / cin_n, ci = i - co*cin_n;
    const float* s = src + (size_t)i*9;
#pragma unroll
    for (int t = 0; t < 9; ++t)
        dst[((size_t)t*cout_n + co)*cin_n + ci] = f2bf(s[t]);
}

extern "C" void kernel_launch(void* const* d_in, const int* in_sizes, int n_in,
                              void* d_out, int out_size, void* d_ws, size_t ws_size,
                              hipStream_t stream)
{
    const float* feature = (const float*)d_in[0];
    const float* w_kc1 = (const float*)d_in[1];
    const float* b_kc1 = (const float*)d_in[2];
    const float* w_kc2 = (const float*)d_in[3];
    const float* b_kc2 = (const float*)d_in[4];
    const float* w_c1  = (const float*)d_in[5];
    const float* b_c1  = (const float*)d_in[6];
    const float* w_c2  = (const float*)d_in[7];
    const float* b_c2  = (const float*)d_in[8];
    const float* w_c3  = (const float*)d_in[9];
    const float* b_c3  = (const float*)d_in[10];
    float* out = (float*)d_out;
    char* ws = (char*)d_ws;

    size_t off = 0;
    auto alloc = [&](size_t bytes) -> void* {
        void* p = ws + off; off += (bytes + 255) & ~(size_t)255; return p;
    };
    short* wt1   = (short*)alloc((size_t)9*64*128*2);
    short* wt2   = (short*)alloc((size_t)9*576*64*2);
    short* wtc1  = (short*)alloc((size_t)9*128*128*2);
    short* wtc2  = (short*)alloc((size_t)9*64*64*2);
    short* wtc3  = (short*)alloc((size_t)9*64*64*2);
    char*  zbase = ws + off;                  // contiguous zero-init block
    short* featX   = (short*)alloc((size_t)PHW*64*2);
    short* fpinit  = (short*)alloc((size_t)PHW*64*2);
    short* fpstate = (short*)alloc((size_t)PHW*64*2);
    short* t1      = (short*)alloc((size_t)PHW*64*2);
    short* fpmid   = (short*)alloc((size_t)PHW*64*2);
    short* fusion  = (short*)alloc((size_t)PHW*128*2);
    size_t zbytes = (size_t)((ws + off) - zbase);
    float* tmp4 = (float*)alloc((size_t)HWSZ*64*4);
    (void)ws_size; (void)in_sizes; (void)n_in; (void)out_size;

    hipMemsetAsync(zbase, 0, zbytes, stream);   // borders of padded buffers = 0
    wtxk<<<(64*128 + 255)/256, 256, 0, stream>>>(w_kc1, wt1, 64, 128);
    wtxk<<<(576*64 + 255)/256, 256, 0, stream>>>(w_kc2, wt2, 576, 64);
    wtxk<<<(128*128 + 255)/256, 256, 0, stream>>>(w_c1, wtc1, 128, 128);
    wtxk<<<(64*64 + 255)/256, 256, 0, stream>>>(w_c2, wtc2, 64, 64);
    wtxk<<<(64*64 + 255)/256, 256, 0, stream>>>(w_c3, wtc3, 64, 64);
    tonhwck<<<576, 64, 0, stream>>>(feature + (size_t)9*CHW, fpinit);

    for (int i = 8; i >= 0; --i) {
        const short* fpin = (i == 8) ? fpinit : fpstate;
        tonhwck<<<576, 64, 0, stream>>>(feature + (size_t)i*CHW, featX);
        // t1 = lrelu(conv(concat(x, fp), w_kc1) + b)
        convk<128, 64, 1, 0><<<384, 128, 0, stream>>>(featX, 64, 0, fpin, 64, 0,
            wt1, b_kc1, t1, 1, PW, 64, 1, nullptr, 0, nullptr, nullptr, nullptr);
        // fpmid = kernel_conv(fp, conv(t1, w_kc2) + b)   [fused, kp never stored]
        kckconvk<<<384, 128, 0, stream>>>(t1, wt2, b_kc2, fpin, fpmid);
        // fusion = lrelu(conv(concat(x, fpmid), w_c1) + b)
        convk<128, 128, 2, 0><<<384, 128, 0, stream>>>(featX, 64, 0, fpmid, 64, 0,
            wtc1, b_c1, fusion, 1, PW, 128, 1, nullptr, 0, nullptr, nullptr, nullptr);
        // tmp4 = p1 * sigmoid(conv(p1, w_c2) + b)
        convk<64, 64, 1, 2><<<384, 128, 0, stream>>>(fusion, 128, 0, nullptr, 0, 0,
            wtc2, b_c2, nullptr, 0, 0, 0, 0, fusion, 0, tmp4, nullptr, nullptr);
        // out[:,i] = fpstate = p2 * sigmoid(conv(p2, w_c3) + b) + tmp4
        convk<64, 64, 1, 3><<<384, 128, 0, stream>>>(fusion, 128, 64, nullptr, 0, 0,
            wtc3, b_c3, nullptr, 0, 0, 0, 0, fusion, 64, tmp4,
            out + (size_t)i*CHW, fpstate);
    }
    hipMemcpyAsync(out + (size_t)9*CHW, feature + (size_t)9*CHW,
                   (size_t)CHW*sizeof(float), hipMemcpyDeviceToDevice, stream);
}

// Round 4
// 1525.489 us; speedup vs baseline: 1.6121x; 1.6121x over previous
//
#include <hip/hip_runtime.h>

#define HH 192
#define WW 192
#define PW 194
#define HWSZ (HH*WW)        // 36864
#define PHW (PW*PW)         // 37636
#define CHW (64*HWSZ)       // 2359296 per frame

typedef __attribute__((ext_vector_type(8))) short bf16x8;
typedef __attribute__((ext_vector_type(4))) short bf16x4;
typedef __attribute__((ext_vector_type(4))) float f32x4;
typedef __attribute__((ext_vector_type(4))) unsigned int u32x4;

typedef __attribute__((address_space(3))) void as3_void;
typedef __attribute__((address_space(1))) const void as1_cvoid;

__device__ __forceinline__ float bf2f(short h) {
    union { unsigned u; float f; } c; c.u = ((unsigned)(unsigned short)h) << 16; return c.f;
}
__device__ __forceinline__ short f2bf(float f) {
    union { float f; unsigned u; } c; c.f = f;
    unsigned u = c.u;
    return (short)((u + 0x7FFFu + ((u >> 16) & 1u)) >> 16);
}
__device__ __forceinline__ float sigm(float v) {
    return 1.f / (1.f + __expf(-v));
}

// ---------------------------------------------------------------------------
// Weight staging: phys layout (from wtxk) is [kb][9][COUT][8 slots][8] bf16
// with slot_phys = slot_log ^ (cout & 7)  (bank swizzle pre-baked -> staging
// is a LINEAR copy, ds_read applies the XOR; both-sides rule).
// Stage one kb (9*COUT_TILE(=64)*64 shorts = 73,728 B) into LDS.
// ---------------------------------------------------------------------------
template<int COUT>
__device__ __forceinline__ void stagew(short* lds, const short* wt, int kb, int mt,
                                       int tid, int wv)
{
    const short* wbase = wt + ((size_t)(kb*9)*COUT + mt*64)*64;
#pragma unroll
    for (int i = 0; i < 18; ++i) {
        int q = i*256 + tid;                    // granule 0..4607
        const short* gp = wbase + (size_t)(q >> 9)*COUT*64 + (q & 511)*8;
        __builtin_amdgcn_global_load_lds((as1_cvoid*)gp,
            (as3_void*)(lds + (i*256 + wv*64)*8), 16, 0, 0);
    }
}

// ---------------------------------------------------------------------------
// Implicit-GEMM 3x3 SAME conv, weights in LDS, B-fragments direct from
// padded-NHWC bf16 global. Block = 256 thr (4 waves), BN = 192 (full row),
// BM = 64 couts (tile mt = blockIdx.x / HH). K in 64-cin blocks (KB).
// Epilogue: bias (+optional lrelu) -> bf16 store.
// ---------------------------------------------------------------------------
template<int KB, int COUT>
__global__ __launch_bounds__(256, 2)
void convk(const short* __restrict__ in0, int cs0, int cb0,
           const short* __restrict__ in1, int cs1, int cb1,
           const short* __restrict__ wt, const float* __restrict__ bias,
           short* __restrict__ outb, int pado, int rowW, int cdst, int lrelu)
{
    __shared__ __align__(16) short lds[9*64*64];   // 73,728 B
    const int tid = threadIdx.x;
    const int l  = tid & 63, wv = tid >> 6;
    const int lr = l & 15,  lg = l >> 4;
    const int y  = blockIdx.x % HH;
    const int mt = blockIdx.x / HH;

    f32x4 acc[4][3];
#pragma unroll
    for (int a = 0; a < 4; ++a)
#pragma unroll
        for (int b = 0; b < 3; ++b) acc[a][b] = f32x4{0.f,0.f,0.f,0.f};

#pragma unroll 1
    for (int kb = 0; kb < KB; ++kb) {
        const short* src = (kb == 0) ? in0 : in1;
        const int cs = (kb == 0) ? cs0 : cs1;
        const int cb = (kb == 0) ? cb0 : cb1;
        if (kb) __syncthreads();
        stagew<COUT>(lds, wt, kb, mt, tid, wv);
        __syncthreads();
#pragma unroll
        for (int dy = 0; dy < 3; ++dy)
#pragma unroll
        for (int dx = 0; dx < 3; ++dx) {
            const int tap = dy*3 + dx;
#pragma unroll
            for (int ks = 0; ks < 2; ++ks) {
                bf16x8 bv[3];
#pragma unroll
                for (int nf = 0; nf < 3; ++nf) {
                    int px = wv*48 + nf*16 + lr + dx;
                    bv[nf] = *reinterpret_cast<const bf16x8*>(
                        src + (size_t)((y+dy)*PW + px)*cs + cb + ks*32 + lg*8);
                }
                const int s = ks*4 + lg;
#pragma unroll
                for (int mf = 0; mf < 4; ++mf) {
                    int row = mf*16 + lr;
                    bf16x8 av = *reinterpret_cast<const bf16x8*>(
                        &lds[(tap*64 + row)*64 + ((s ^ (row & 7))*8)]);
                    acc[mf][0] = __builtin_amdgcn_mfma_f32_16x16x32_bf16(av, bv[0], acc[mf][0], 0,0,0);
                    acc[mf][1] = __builtin_amdgcn_mfma_f32_16x16x32_bf16(av, bv[1], acc[mf][1], 0,0,0);
                    acc[mf][2] = __builtin_amdgcn_mfma_f32_16x16x32_bf16(av, bv[2], acc[mf][2], 0,0,0);
                }
            }
        }
    }

    // epilogue: D row(cout) = lg*4 + j (+mf*16+mt*64), col(pixel) = lr
#pragma unroll
    for (int mf = 0; mf < 4; ++mf) {
        const int coutb = mt*64 + mf*16 + lg*4;
        f32x4 bv = *reinterpret_cast<const f32x4*>(bias + coutb);
#pragma unroll
        for (int nf = 0; nf < 3; ++nf) {
            const int x = wv*48 + nf*16 + lr;
            bf16x4 pk;
#pragma unroll
            for (int j = 0; j < 4; ++j) {
                float t = acc[mf][nf][j] + bv[j];
                if (lrelu) t = (t >= 0.f) ? t : 0.1f*t;
                pk[j] = f2bf(t);
            }
            *reinterpret_cast<bf16x4*>(outb + (size_t)((y+pado)*rowW + (x+pado))*cdst + coutb) = pk;
        }
    }
}

// ---------------------------------------------------------------------------
// Fused dual-gate kernel: r = p1*sig(conv(p1,w_c2)+b2) + p2*sig(conv(p2,w_c3)+b3)
// p1/p2 = halves of fusion (cs=128). Writes d_out frame (NCHW f32) + fpstate
// (padded NHWC bf16). wg = [2][9][64][64] phys-swizzled (wtc2, wtc3).
// ---------------------------------------------------------------------------
__global__ __launch_bounds__(256, 2)
void gatek(const short* __restrict__ fus, const short* __restrict__ wg,
           const float* __restrict__ b2, const float* __restrict__ b3,
           float* __restrict__ dml, short* __restrict__ fpst)
{
    __shared__ __align__(16) short lds[9*64*64];
    const int tid = threadIdx.x;
    const int l  = tid & 63, wv = tid >> 6;
    const int lr = l & 15,  lg = l >> 4;
    const int y  = blockIdx.x;

    f32x4 acc1[4][3], acc2[4][3];
#pragma unroll
    for (int a = 0; a < 4; ++a)
#pragma unroll
        for (int b = 0; b < 3; ++b) { acc1[a][b] = f32x4{0.f,0.f,0.f,0.f}; acc2[a][b] = f32x4{0.f,0.f,0.f,0.f}; }

#pragma unroll 1
    for (int g = 0; g < 2; ++g) {
        if (g) __syncthreads();
        stagew<64>(lds, wg + (size_t)g*9*64*64, 0, 0, tid, wv);
        __syncthreads();
#pragma unroll
        for (int dy = 0; dy < 3; ++dy)
#pragma unroll
        for (int dx = 0; dx < 3; ++dx) {
            const int tap = dy*3 + dx;
#pragma unroll
            for (int ks = 0; ks < 2; ++ks) {
                bf16x8 bv[3];
#pragma unroll
                for (int nf = 0; nf < 3; ++nf) {
                    int px = wv*48 + nf*16 + lr + dx;
                    bv[nf] = *reinterpret_cast<const bf16x8*>(
                        fus + (size_t)((y+dy)*PW + px)*128 + g*64 + ks*32 + lg*8);
                }
                const int s = ks*4 + lg;
#pragma unroll
                for (int mf = 0; mf < 4; ++mf) {
                    int row = mf*16 + lr;
                    bf16x8 av = *reinterpret_cast<const bf16x8*>(
                        &lds[(tap*64 + row)*64 + ((s ^ (row & 7))*8)]);
                    f32x4* ac = g ? &acc2[mf][0] : &acc1[mf][0];
                    ac[0] = __builtin_amdgcn_mfma_f32_16x16x32_bf16(av, bv[0], ac[0], 0,0,0);
                    ac[1] = __builtin_amdgcn_mfma_f32_16x16x32_bf16(av, bv[1], ac[1], 0,0,0);
                    ac[2] = __builtin_amdgcn_mfma_f32_16x16x32_bf16(av, bv[2], ac[2], 0,0,0);
                }
            }
        }
    }

#pragma unroll
    for (int mf = 0; mf < 4; ++mf) {
        const int c = mf*16 + lg*4;
        f32x4 v2 = *reinterpret_cast<const f32x4*>(b2 + c);
        f32x4 v3 = *reinterpret_cast<const f32x4*>(b3 + c);
#pragma unroll
        for (int nf = 0; nf < 3; ++nf) {
            const int x = wv*48 + nf*16 + lr;
            bf16x4 p1 = *reinterpret_cast<const bf16x4*>(fus + (size_t)((y+1)*PW + (x+1))*128 + c);
            bf16x4 p2 = *reinterpret_cast<const bf16x4*>(fus + (size_t)((y+1)*PW + (x+1))*128 + 64 + c);
            bf16x4 pk;
#pragma unroll
            for (int j = 0; j < 4; ++j) {
                float r = bf2f(p1[j]) * sigm(acc1[mf][nf][j] + v2[j])
                        + bf2f(p2[j]) * sigm(acc2[mf][nf][j] + v3[j]);
                dml[(size_t)(c + j)*HWSZ + y*WW + x] = r;
                pk[j] = f2bf(r);
            }
            *reinterpret_cast<bf16x4*>(fpst + (size_t)((y+1)*PW + (x+1))*64 + c) = pk;
        }
    }
}

// ---------------------------------------------------------------------------
// Dynamic per-pixel 3x3 kernel conv: out[c,y,x] = sum_t kp[y,x,t*64+c]*fp[y+dy,x+dx,c]
// kp: unpadded NHWC [HW][576] bf16 (bias already added); fp/out: padded NHWC
// ---------------------------------------------------------------------------
__global__ __launch_bounds__(256)
void kconvk(const short* __restrict__ kp, const short* __restrict__ fp,
            short* __restrict__ outp)
{
    int t  = blockIdx.x*256 + threadIdx.x;
    int cg = t & 7, pix = t >> 3;
    int y = pix / WW, x = pix - y*WW;
    float acc[8];
#pragma unroll
    for (int e = 0; e < 8; ++e) acc[e] = 0.f;
    const short* kpp = kp + (size_t)pix*576 + cg*8;
#pragma unroll
    for (int tap = 0; tap < 9; ++tap) {
        int dy = tap / 3, dx = tap - dy*3;
        bf16x8 kv = *reinterpret_cast<const bf16x8*>(kpp + tap*64);
        bf16x8 fv = *reinterpret_cast<const bf16x8*>(fp + (size_t)((y+dy)*PW + (x+dx))*64 + cg*8);
#pragma unroll
        for (int e = 0; e < 8; ++e) acc[e] += bf2f(kv[e]) * bf2f(fv[e]);
    }
    bf16x8 o;
#pragma unroll
    for (int e = 0; e < 8; ++e) o[e] = f2bf(acc[e]);
    *reinterpret_cast<bf16x8*>(outp + (size_t)((y+1)*PW + (x+1))*64 + cg*8) = o;
}

// ---------------------------------------------------------------------------
// NCHW f32 frame -> padded NHWC bf16 (interior only; border pre-zeroed)
// ---------------------------------------------------------------------------
__global__ __launch_bounds__(64)
void tonhwck(const float* __restrict__ src, short* __restrict__ dst)
{
    int b = blockIdx.x;
    int y = b / 3, x = (b - y*3)*64 + threadIdx.x;
    unsigned pk[32];
#pragma unroll
    for (int c = 0; c < 64; ++c) {
        unsigned h = (unsigned)(unsigned short)f2bf(src[(size_t)c*HWSZ + y*WW + x]);
        if (c & 1) pk[c>>1] |= h << 16; else pk[c>>1] = h;
    }
    u32x4* d = reinterpret_cast<u32x4*>(dst + (size_t)((y+1)*PW + (x+1))*64);
#pragma unroll
    for (int q = 0; q < 8; ++q) d[q] = u32x4{pk[4*q], pk[4*q+1], pk[4*q+2], pk[4*q+3]};
}

// ---------------------------------------------------------------------------
// weight [COUT][CIN][3][3] f32 -> phys [kb][9][COUT][slot^(co&7)][8] bf16
// ---------------------------------------------------------------------------
__global__ void wtxk(const float* __restrict__ src, short* __restrict__ dst,
                     int cout_n, int cin_n)
{
    int i = blockIdx.x*256 + threadIdx.x;
    if (i >= cout_n*cin_n) return;
    int co = i / cin_n, ci = i - co*cin_n;
    int kb = ci >> 6, cl = ci & 63, s = cl >> 3, e = cl & 7;
    const float* sp = src + (size_t)i*9;
    size_t base = ((size_t)(kb*9)*cout_n + co)*64 + ((s ^ (co & 7))*8) + e;
#pragma unroll
    for (int t = 0; t < 9; ++t)
        dst[base + (size_t)t*cout_n*64] = f2bf(sp[t]);
}

extern "C" void kernel_launch(void* const* d_in, const int* in_sizes, int n_in,
                              void* d_out, int out_size, void* d_ws, size_t ws_size,
                              hipStream_t stream)
{
    const float* feature = (const float*)d_in[0];
    const float* w_kc1 = (const float*)d_in[1];
    const float* b_kc1 = (const float*)d_in[2];
    const float* w_kc2 = (const float*)d_in[3];
    const float* b_kc2 = (const float*)d_in[4];
    const float* w_c1  = (const float*)d_in[5];
    const float* b_c1  = (const float*)d_in[6];
    const float* w_c2  = (const float*)d_in[7];
    const float* b_c2  = (const float*)d_in[8];
    const float* w_c3  = (const float*)d_in[9];
    const float* b_c3  = (const float*)d_in[10];
    float* out = (float*)d_out;
    char* ws = (char*)d_ws;

    size_t off = 0;
    auto alloc = [&](size_t bytes) -> void* {
        void* p = ws + off; off += (bytes + 255) & ~(size_t)255; return p;
    };
    short* wt1   = (short*)alloc((size_t)2*9*64*64*2);    // conv1 (CIN=128,COUT=64)
    short* wt2   = (short*)alloc((size_t)9*576*64*2);     // kc2  (CIN=64, COUT=576)
    short* wtc1  = (short*)alloc((size_t)2*9*128*64*2);   // c1   (CIN=128,COUT=128)
    short* wg    = (short*)alloc((size_t)2*9*64*64*2);    // c2,c3 concatenated
    char*  zbase = ws + off;                  // contiguous zero-init block
    short* featX   = (short*)alloc((size_t)PHW*64*2);
    short* fpinit  = (short*)alloc((size_t)PHW*64*2);
    short* fpstate = (short*)alloc((size_t)PHW*64*2);
    short* t1      = (short*)alloc((size_t)PHW*64*2);
    short* fpmid   = (short*)alloc((size_t)PHW*64*2);
    short* fusion  = (short*)alloc((size_t)PHW*128*2);
    size_t zbytes = (size_t)((ws + off) - zbase);
    short* kp   = (short*)alloc((size_t)HWSZ*576*2);
    (void)ws_size; (void)in_sizes; (void)n_in; (void)out_size;

    hipMemsetAsync(zbase, 0, zbytes, stream);   // borders of padded buffers = 0
    wtxk<<<(64*128 + 255)/256, 256, 0, stream>>>(w_kc1, wt1, 64, 128);
    wtxk<<<(576*64 + 255)/256, 256, 0, stream>>>(w_kc2, wt2, 576, 64);
    wtxk<<<(128*128 + 255)/256, 256, 0, stream>>>(w_c1, wtc1, 128, 128);
    wtxk<<<(64*64 + 255)/256, 256, 0, stream>>>(w_c2, wg, 64, 64);
    wtxk<<<(64*64 + 255)/256, 256, 0, stream>>>(w_c3, wg + (size_t)9*64*64, 64, 64);
    tonhwck<<<576, 64, 0, stream>>>(feature + (size_t)9*CHW, fpinit);

    for (int i = 8; i >= 0; --i) {
        const short* fpin = (i == 8) ? fpinit : fpstate;
        tonhwck<<<576, 64, 0, stream>>>(feature + (size_t)i*CHW, featX);
        // t1 = lrelu(conv(concat(x, fp), w_kc1) + b)
        convk<2, 64><<<HH, 256, 0, stream>>>(featX, 64, 0, fpin, 64, 0,
            wt1, b_kc1, t1, 1, PW, 64, 1);
        // kp = conv(t1, w_kc2) + b
        convk<1, 576><<<9*HH, 256, 0, stream>>>(t1, 64, 0, nullptr, 0, 0,
            wt2, b_kc2, kp, 0, WW, 576, 0);
        // fpmid = kernel_conv(fp, kp)
        kconvk<<<1152, 256, 0, stream>>>(kp, fpin, fpmid);
        // fusion = lrelu(conv(concat(x, fpmid), w_c1) + b)
        convk<2, 128><<<2*HH, 256, 0, stream>>>(featX, 64, 0, fpmid, 64, 0,
            wtc1, b_c1, fusion, 1, PW, 128, 1);
        // out[:,i] = fpstate = p1*sig(conv(p1,w_c2)+b2) + p2*sig(conv(p2,w_c3)+b3)
        gatek<<<HH, 256, 0, stream>>>(fusion, wg, b_c2, b_c3,
            out + (size_t)i*CHW, fpstate);
    }
    hipMemcpyAsync(out + (size_t)9*CHW, feature + (size_t)9*CHW,
                   (size_t)CHW*sizeof(float), hipMemcpyDeviceToDevice, stream);
}